// Round 10
// baseline (45818.988 us; speedup 1.0000x reference)
//
#include <hip/hip_runtime.h>

namespace {

constexpr int kT = 256;

typedef float f2 __attribute__((ext_vector_type(2)));
typedef float f4 __attribute__((ext_vector_type(4)));

__device__ __forceinline__ float fast_tanh(float x) {
    float e = __expf(2.0f * x);
    return 1.0f - 2.0f * __builtin_amdgcn_rcpf(e + 1.0f);
}

__device__ __forceinline__ float dpp_xor1(float x) {
    return __builtin_bit_cast(float, __builtin_amdgcn_update_dpp(
        0, __builtin_bit_cast(int, x), 0xB1, 0xF, 0xF, true)); // quad [1,0,3,2]
}
__device__ __forceinline__ float dpp_xor2(float x) {
    return __builtin_bit_cast(float, __builtin_amdgcn_update_dpp(
        0, __builtin_bit_cast(int, x), 0x4E, 0xF, 0xF, true)); // quad [2,3,0,1]
}
__device__ __forceinline__ float dpp_ror8(float x) {           // lane ^ 8 within row16
    return __builtin_bit_cast(float, __builtin_amdgcn_update_dpp(
        0, __builtin_bit_cast(int, x), 0x128, 0xF, 0xF, true)); // row_ror:8
}
template <int PAT>
__device__ __forceinline__ float swz(float x) {
    return __builtin_bit_cast(float,
        __builtin_amdgcn_ds_swizzle(__builtin_bit_cast(int, x), PAT));
}
__device__ __forceinline__ float read_lane(float x, int lane) {
    return __builtin_bit_cast(float,
        __builtin_amdgcn_readlane(__builtin_bit_cast(int, x), lane));
}

// h storage, k-major with rows in the fast axis: element (k, r) at float
// offset 4*k + 4*(k>>4) + r. One ds_read_b128 at k yields h[k][r=0..3]
// (f4 over rows -> no k-parity horizontal add). The per-16k-chunk pad
// 4*(k>>4) puts the 8 kg read-bases (stride 68) on 8 distinct bank-quads
// = all 32 banks exactly once = conflict-free.
//
// REGISTER DISCIPLINE (hard-won, r1/r2/r5/r9): a 512-thread block is 8
// waves = 2 waves/SIMD ALWAYS -> hard 128 VGPR/wave cap (launch_bounds
// can't lift it). Persistent arrays (~110 regs incl. wgt 96) fit ONLY if
// transient pressure stays low: r9's 16-deep unrolled ds_read chain (64
// transient regs) forced wholesale wgt spill (128-pin + 69 GB FETCH).
// Fix here: chunk the k-loop 4-at-a-time with sched_barrier(0) so at most
// 4 b128 loads (16 regs) are in flight. r7 also measured: a 2nd block/CU
// never co-resides (occupancy is NOT a lever) - keep 256 blocks x 512.
__device__ __forceinline__ int haddr(int k, int r) {
    return 4 * k + 4 * (k >> 4) + r;
}

__global__ __launch_bounds__(512, 1) void hybrid_ode_kernel(
    const float* __restrict__ y0,
    const float* __restrict__ t_span,
    const float* __restrict__ meal,
    const float* __restrict__ tvns,
    const float* __restrict__ W_in, const float* __restrict__ b_in,
    const float* __restrict__ W_h,  const float* __restrict__ b_h,
    const float* __restrict__ W_out,const float* __restrict__ b_out,
    float* __restrict__ out)
{
    const int tid = threadIdx.x;
    const int w   = tid >> 6;          // wave 0..7
    const int l   = tid & 63;
    const int kg  = l & 7;             // k-chunk (16 k's)
    const int jgl = l >> 3;            // 0..7 j-group within wave
    const int kch = kg >> 2;           // kg bit2 (j-XOR key, 1 bit)
    const int jb  = (w * 8 + jgl) * 2; // thread's 2 j's: jb, jb+1 (XOR-permuted)
    const int rw  = w & 3;             // batch row this wave carries
    const int row = blockIdx.x * 4 + rw;

    // produced output slot after reduce-scatter: r_p = kg&3, j_p = jb+kch
    const int r_p = kg & 3;
    const int j_p = jb + kch;
    const int waddr = haddr(j_p, r_p);
    const bool pb0 = (kg & 1) != 0;
    const bool pb1 = (kg & 2) != 0;

    __shared__ __align__(16) float hp0[544];
    __shared__ __align__(16) float hp1[544];

    // ---- one-time weight staging into registers (f2 over jj).
    // wgt[ll][ki].x -> col jb + (0^kch), .y -> col jb + (1^kch), k = 16*kg+ki.
    // The j-XOR makes the final butterfly stage uniform (no keep/give).
    f2 wgt[3][16];
    #pragma unroll
    for (int ll = 0; ll < 3; ++ll)
        #pragma unroll
        for (int ki = 0; ki < 16; ++ki) {
            const float* p = W_h + (size_t)(ll * 128 + 16 * kg + ki) * 128 + jb;
            f2 v; v.x = p[0 ^ kch]; v.y = p[1 ^ kch];
            wgt[ll][ki] = v;
        }

    // Input layer is register-direct: waves 0..3 produce rows 0..3, cols
    // 0..63; waves 4..7 same rows, cols 64..127. x-vector is wave-uniform
    // in registers. The two y3 terms (k=4, k=7) fold into one staged weight.
    const int j2 = l + 64 * (w >> 2);
    const int waddr2 = haddr(j2, rw);
    float win[8];
    win[0] = W_in[0 * 128 + j2];                         // t
    win[1] = W_in[1 * 128 + j2];                         // y0
    win[2] = W_in[2 * 128 + j2];                         // y1
    win[3] = W_in[3 * 128 + j2];                         // y2
    win[4] = W_in[4 * 128 + j2] + W_in[7 * 128 + j2];    // y3 (+ glp1=y3)
    win[5] = W_in[5 * 128 + j2];                         // y4
    win[6] = W_in[6 * 128 + j2];                         // y5
    win[7] = W_in[8 * 128 + j2];                         // v
    const float bin = b_in[j2];

    float bh[3];
    #pragma unroll
    for (int ll = 0; ll < 3; ++ll) bh[ll] = b_h[ll * 128 + j_p];

    // output layer: XOR-permuted weights for a 3-bit reduce-scatter (s lands at l&7)
    const int s8 = l & 7;
    float wo0p[8], wo1p[8], bo[6];
    #pragma unroll
    for (int p = 0; p < 8; ++p) {
        const int q = p ^ s8;
        wo0p[p] = (q < 6) ? W_out[l * 6 + q] : 0.0f;
        wo1p[p] = (q < 6) ? W_out[(l + 64) * 6 + q] : 0.0f;
    }
    #pragma unroll
    for (int s = 0; s < 6; ++s) bo[s] = b_out[s];
    const int oaddrA = haddr(l, 0);        // + rw at use
    const int oaddrB = haddr(l + 64, 0);   // = oaddrA + 272

    float y[6];
    #pragma unroll
    for (int s = 0; s < 6; ++s) y[s] = y0[row * 6 + s];

    if (w < 4 && l == 0) {
        #pragma unroll
        for (int s = 0; s < 6; ++s) out[(size_t)row * kT * 6 + s] = y[s];
    }

    const float* mrow = meal + (size_t)row * kT;
    const float* vrow = tvns + (size_t)row * kT;

    auto dyn = [&](float t, const float* yc, float m, float v, float* d) {
        // ---- input layer 9->128, register-direct. Prior hp0 readers
        // (layer ll=2) are ordered by the previous dyn's post-L3 barrier.
        {
            float s = bin + t * win[0];
            s += yc[0] * win[1] + yc[1] * win[2] + yc[2] * win[3];
            s += yc[3] * win[4] + yc[4] * win[5] + yc[5] * win[6];
            s += v * win[7];
            hp0[waddr2] = fast_tanh(s);
        }
        __syncthreads();

        // ---- 3 hidden layers 128->128 (4 rows vectorized in f4 accumulators)
        #pragma unroll
        for (int ll = 0; ll < 3; ++ll) {
            const float* rb = (ll & 1) ? hp1 : hp0;
            float*       wb = (ll & 1) ? hp0 : hp1;

            // 16x ds_read_b128 in 4 chunks of 4; sched_barrier(0) between
            // chunks bounds outstanding loads to 4 (16 transient VGPRs) so
            // the 96-reg wgt array stays resident (see header note / r9).
            const float* hb = rb + 68 * kg;
            f4 acc0 = {0.f, 0.f, 0.f, 0.f};
            f4 acc1 = {0.f, 0.f, 0.f, 0.f};
            #pragma unroll
            for (int kb = 0; kb < 4; ++kb) {
                f4 q0 = *(const f4*)(hb + 16 * kb);
                f4 q1 = *(const f4*)(hb + 16 * kb + 4);
                f4 q2 = *(const f4*)(hb + 16 * kb + 8);
                f4 q3 = *(const f4*)(hb + 16 * kb + 12);
                const f2 w0 = wgt[ll][4 * kb + 0];
                const f2 w1 = wgt[ll][4 * kb + 1];
                const f2 w2 = wgt[ll][4 * kb + 2];
                const f2 w3 = wgt[ll][4 * kb + 3];
                acc0 += q0 * w0.x;  acc1 += q0 * w0.y;
                acc0 += q1 * w1.x;  acc1 += q1 * w1.y;
                acc0 += q2 * w2.x;  acc1 += q2 * w2.y;
                acc0 += q3 * w3.x;  acc1 += q3 * w3.y;
                __builtin_amdgcn_sched_barrier(0);
            }

            // 3-stage reduce-scatter over the 8 kg lanes (same jgl group):
            // kg-bit0/1 key the r bits (keep/give selects); kg-bit2 keys jj,
            // uniform thanks to the jj^kch weight permutation.
            float B0[2], B1[2];
            #pragma unroll
            for (int i = 0; i < 2; ++i) {
                float k0 = pb0 ? acc0[2*i+1] : acc0[2*i];
                float g0 = pb0 ? acc0[2*i]   : acc0[2*i+1];
                B0[i] = k0 + dpp_xor1(g0);
                float k1 = pb0 ? acc1[2*i+1] : acc1[2*i];
                float g1 = pb0 ? acc1[2*i]   : acc1[2*i+1];
                B1[i] = k1 + dpp_xor1(g1);
            }
            const float kc0 = pb1 ? B0[1] : B0[0];
            const float gc0 = pb1 ? B0[0] : B0[1];
            const float C0  = kc0 + dpp_xor2(gc0);
            const float kc1 = pb1 ? B1[1] : B1[0];
            const float gc1 = pb1 ? B1[0] : B1[1];
            const float C1  = kc1 + dpp_xor2(gc1);
            const float S   = C0 + swz<0x101F>(C1);   // xor4, uniform

            wb[waddr] = fast_tanh(S + bh[ll]);
            __syncthreads();
        }

        // ---- output layer 128->6 for this wave's row; h3 lives in hp1.
        // Reduce-scatter s to lane s8 (uniform, XOR'd weights), all-reduce
        // the 8-lane groups, then readlane-broadcast p[0..5] as wave scalars.
        const float hA = hp1[oaddrA + rw];
        const float hB = hp1[oaddrB + rw];
        float P[8];
        #pragma unroll
        for (int p = 0; p < 8; ++p) P[p] = hA * wo0p[p] + hB * wo1p[p];
        float Q[4];
        #pragma unroll
        for (int i = 0; i < 4; ++i) Q[i] = P[2*i] + dpp_xor1(P[2*i+1]);
        const float R0 = Q[0] + dpp_xor2(Q[1]);
        const float R1 = Q[2] + dpp_xor2(Q[3]);
        float S = R0 + swz<0x101F>(R1);   // xor4
        S += dpp_ror8(S);                 // xor8
        S += swz<0x401F>(S);              // xor16
        S += __shfl_xor(S, 32);           // xor32

        const float p0 = read_lane(S, 0);
        const float p1 = read_lane(S, 1);
        const float p2 = read_lane(S, 2);
        const float p3 = read_lane(S, 3);
        const float p4 = read_lane(S, 4);
        const float p5 = read_lane(S, 5);

        const float G = yc[0], I = yc[1], N = yc[2], L = yc[3], GE = yc[4], F = yc[5];
        d[0] = -0.01f*I*G + 0.05f*GE                                    + p0 + bo[0];
        d[1] = (G/(100.0f+G))*(1.0f + 2.0f*L/(5.0f+L)) - 0.1f*I         + p1 + bo[1];
        d[2] = -0.05f*N                                                 + p2 + bo[2];
        d[3] = 0.05f*GE - 0.2f*L                                        + p3 + bo[3];
        d[4] = m - 0.05f*GE                                             + p4 + bo[4];
        d[5] = -0.01f*I*F                                               + p5 + bo[5];
    };

    for (int i = 0; i < kT - 1; ++i) {
        const float t0 = t_span[i], t1 = t_span[i + 1];
        const float dt = t1 - t0;
        const float m0 = mrow[i], m1 = mrow[i + 1];
        const float v0 = vrow[i], v1 = vrow[i + 1];
        const float tm = t0 + 0.5f * dt;
        const float mm = 0.5f * (m0 + m1), vm = 0.5f * (v0 + v1);

        float d[6], ksum[6], yc[6];

        dyn(t0, y, m0, v0, d);
        #pragma unroll
        for (int s = 0; s < 6; ++s) { ksum[s] = d[s]; yc[s] = y[s] + 0.5f * dt * d[s]; }
        dyn(tm, yc, mm, vm, d);
        #pragma unroll
        for (int s = 0; s < 6; ++s) { ksum[s] += 2.0f * d[s]; yc[s] = y[s] + 0.5f * dt * d[s]; }
        dyn(tm, yc, mm, vm, d);
        #pragma unroll
        for (int s = 0; s < 6; ++s) { ksum[s] += 2.0f * d[s]; yc[s] = y[s] + dt * d[s]; }
        dyn(t1, yc, m1, v1, d);
        #pragma unroll
        for (int s = 0; s < 6; ++s) {
            ksum[s] += d[s];
            y[s] += (dt * (1.0f / 6.0f)) * ksum[s];
        }

        if (w < 4 && l == 0) {
            #pragma unroll
            for (int s = 0; s < 6; ++s)
                out[((size_t)row * kT + (i + 1)) * 6 + s] = y[s];
        }
    }
}

} // namespace

extern "C" void kernel_launch(void* const* d_in, const int* in_sizes, int n_in,
                              void* d_out, int out_size, void* d_ws, size_t ws_size,
                              hipStream_t stream) {
    const float* y0     = (const float*)d_in[0];
    const float* t_span = (const float*)d_in[1];
    const float* meal   = (const float*)d_in[2];
    const float* tvns   = (const float*)d_in[3];
    const float* W_in   = (const float*)d_in[4];
    const float* b_in   = (const float*)d_in[5];
    const float* W_h    = (const float*)d_in[6];
    const float* b_h    = (const float*)d_in[7];
    const float* W_out  = (const float*)d_in[8];
    const float* b_out  = (const float*)d_in[9];
    float* out          = (float*)d_out;

    hipLaunchKernelGGL(hybrid_ode_kernel, dim3(256), dim3(512), 0, stream,
                       y0, t_span, meal, tvns,
                       W_in, b_in, W_h, b_h, W_out, b_out, out);
}

// Round 11
// 2335.900 us; speedup vs baseline: 19.6151x; 19.6151x over previous
//
#include <hip/hip_runtime.h>

namespace {

constexpr int kT = 256;

typedef float f2 __attribute__((ext_vector_type(2)));
typedef float f4 __attribute__((ext_vector_type(4)));

__device__ __forceinline__ float fast_tanh(float x) {
    float e = __expf(2.0f * x);
    return 1.0f - 2.0f * __builtin_amdgcn_rcpf(e + 1.0f);
}

__device__ __forceinline__ float dpp_xor1(float x) {
    return __builtin_bit_cast(float, __builtin_amdgcn_update_dpp(
        0, __builtin_bit_cast(int, x), 0xB1, 0xF, 0xF, true)); // quad [1,0,3,2]
}
__device__ __forceinline__ float dpp_xor2(float x) {
    return __builtin_bit_cast(float, __builtin_amdgcn_update_dpp(
        0, __builtin_bit_cast(int, x), 0x4E, 0xF, 0xF, true)); // quad [2,3,0,1]
}
__device__ __forceinline__ float dpp_ror8(float x) {           // lane ^ 8 within row16
    return __builtin_bit_cast(float, __builtin_amdgcn_update_dpp(
        0, __builtin_bit_cast(int, x), 0x128, 0xF, 0xF, true)); // row_ror:8
}
template <int PAT>
__device__ __forceinline__ float swz(float x) {
    return __builtin_bit_cast(float,
        __builtin_amdgcn_ds_swizzle(__builtin_bit_cast(int, x), PAT));
}
__device__ __forceinline__ float read_lane(float x, int lane) {
    return __builtin_bit_cast(float,
        __builtin_amdgcn_readlane(__builtin_bit_cast(int, x), lane));
}

// h storage: element (k2,r,b) at float offset 8*k2 + 4*(k2>>2) + 2*r + b,
// where k2 = k>>1, b = k&1. f2 pair (k even, k odd) is contiguous; the
// pad 4*(k2>>2) spreads kc-chunks across banks (<=2-way everywhere).
//
// STRUCTURAL LEDGER (hard-won):
//  * 512-thread block = 8 waves = 2 waves/SIMD ALWAYS -> hard 128 VGPR cap.
//    This f2-pair core fits (112); the k-major f4-quad core spills WHOLESALE
//    regardless of launch bounds or sched_barrier load-chunking (r1/r2/r5/
//    r9/r10: 128-pin + 59-70 GB FETCH/dispatch). Do not re-land f4-quad.
//  * Occupancy is NOT a lever: a 2nd block/CU never co-resides (r7: 512
//    blocks ran as 2 sequential passes). Keep 256 blocks x 512 threads.
//  * Butterfly stage ORDER matters: uniform (XOR-permuted jj) stages first
//    while elements are many, keyed (r-bit select) stages last when few:
//    54 -> 36 VALU/layer (this round).
__device__ __forceinline__ int haddr(int j, int r) {
    return 8 * (j >> 1) + 4 * (j >> 3) + 2 * r + (j & 1);
}

__global__ __launch_bounds__(512, 1) void hybrid_ode_kernel(
    const float* __restrict__ y0,
    const float* __restrict__ t_span,
    const float* __restrict__ meal,
    const float* __restrict__ tvns,
    const float* __restrict__ W_in, const float* __restrict__ b_in,
    const float* __restrict__ W_h,  const float* __restrict__ b_h,
    const float* __restrict__ W_out,const float* __restrict__ b_out,
    float* __restrict__ out)
{
    const int tid = threadIdx.x;
    const int w   = tid >> 6;          // wave 0..7
    const int l   = tid & 63;
    const int jgl = l >> 4;            // 0..3 j-group within wave
    const int kc  = l & 15;            // k-chunk (8 k's)
    const int kch = kc >> 2;           // high 2 bits of kc (j-XOR key)
    const int jg  = w * 4 + jgl;       // 0..31
    const int jb  = jg * 4;            // thread's 4 j's: jb..jb+3 (XOR-permuted)
    const int rw  = w & 3;             // batch row this wave carries
    const int row = blockIdx.x * 4 + rw;

    // produced output slot after reduce-scatter
    const int r_p = kc & 3;
    const int j_p = jb + kch;
    const int waddr = haddr(j_p, r_p);
    const bool pb0 = (kc & 1) != 0;
    const bool pb1 = (kc & 2) != 0;

    __shared__ __align__(16) float hp0[576];
    __shared__ __align__(16) float hp1[576];

    // ---- one-time weight staging into registers
    // wgt[ll][ka][jj] holds column j = jb + (jj ^ kch): the j-XOR makes
    // the jj butterfly stages uniform (no keep/give selects there).
    f2 wgt[3][4][4];   // [layer][kpair kappa][jj]: k = 8kc+2*ka (+1)
    #pragma unroll
    for (int ll = 0; ll < 3; ++ll)
        #pragma unroll
        for (int ka = 0; ka < 4; ++ka)
            #pragma unroll
            for (int jj = 0; jj < 4; ++jj) {
                const float* p = W_h + (size_t)(ll * 128 + 8 * kc + 2 * ka) * 128
                               + jb + (jj ^ kch);
                f2 v; v.x = p[0]; v.y = p[128];
                wgt[ll][ka][jj] = v;
            }

    // Input layer is register-direct: waves 0..3 produce rows 0..3, cols
    // 0..63; waves 4..7 same rows, cols 64..127. x-vector is wave-uniform
    // in registers. The two y3 terms (k=4, k=7) fold into one staged weight.
    const int j2 = l + 64 * (w >> 2);
    const int waddr2 = haddr(j2, rw);
    float win[8];
    win[0] = W_in[0 * 128 + j2];                         // t
    win[1] = W_in[1 * 128 + j2];                         // y0
    win[2] = W_in[2 * 128 + j2];                         // y1
    win[3] = W_in[3 * 128 + j2];                         // y2
    win[4] = W_in[4 * 128 + j2] + W_in[7 * 128 + j2];    // y3 (+ glp1=y3)
    win[5] = W_in[5 * 128 + j2];                         // y4
    win[6] = W_in[6 * 128 + j2];                         // y5
    win[7] = W_in[8 * 128 + j2];                         // v
    const float bin = b_in[j2];

    float bh[3];
    #pragma unroll
    for (int ll = 0; ll < 3; ++ll) bh[ll] = b_h[ll * 128 + j_p];

    // output layer: XOR-permuted weights for a 3-bit reduce-scatter (s lands at l&7)
    const int s8 = l & 7;
    float wo0p[8], wo1p[8], bo[6];
    #pragma unroll
    for (int p = 0; p < 8; ++p) {
        const int q = p ^ s8;
        wo0p[p] = (q < 6) ? W_out[l * 6 + q] : 0.0f;
        wo1p[p] = (q < 6) ? W_out[(l + 64) * 6 + q] : 0.0f;
    }
    #pragma unroll
    for (int s = 0; s < 6; ++s) bo[s] = b_out[s];
    const int oaddr = 8 * (l >> 1) + 4 * (l >> 3) + (l & 1);  // + 2*rw at use

    float y[6];
    #pragma unroll
    for (int s = 0; s < 6; ++s) y[s] = y0[row * 6 + s];

    if (w < 4 && l == 0) {
        #pragma unroll
        for (int s = 0; s < 6; ++s) out[(size_t)row * kT * 6 + s] = y[s];
    }

    const float* mrow = meal + (size_t)row * kT;
    const float* vrow = tvns + (size_t)row * kT;

    auto dyn = [&](float t, const float* yc, float m, float v, float* d) {
        // ---- input layer 9->128, register-direct. Prior hp0 readers
        // (layer ll=2) are ordered by the previous dyn's post-L3 barrier.
        {
            float s = bin + t * win[0];
            s += yc[0] * win[1] + yc[1] * win[2] + yc[2] * win[3];
            s += yc[3] * win[4] + yc[4] * win[5] + yc[5] * win[6];
            s += v * win[7];
            hp0[waddr2] = fast_tanh(s);
        }
        __syncthreads();

        // ---- 3 hidden layers 128->128
        #pragma unroll
        for (int ll = 0; ll < 3; ++ll) {
            const float* rb = (ll & 1) ? hp1 : hp0;
            float*       wb = (ll & 1) ? hp0 : hp1;

            f2 acc[4][4];   // [jj][r], packed over k-parity
            #pragma unroll
            for (int ka = 0; ka < 4; ++ka) {
                const int base = 36 * kc + 8 * ka;
                f4 q0 = *(const f4*)(rb + base);
                f4 q1 = *(const f4*)(rb + base + 4);
                f2 h0 = __builtin_shufflevector(q0, q0, 0, 1);
                f2 h1 = __builtin_shufflevector(q0, q0, 2, 3);
                f2 h2 = __builtin_shufflevector(q1, q1, 0, 1);
                f2 h3 = __builtin_shufflevector(q1, q1, 2, 3);
                #pragma unroll
                for (int jj = 0; jj < 4; ++jj) {
                    const f2 wv = wgt[ll][ka][jj];
                    if (ka == 0) {
                        acc[jj][0] = h0 * wv;
                        acc[jj][1] = h1 * wv;
                        acc[jj][2] = h2 * wv;
                        acc[jj][3] = h3 * wv;
                    } else {
                        acc[jj][0] = h0 * wv + acc[jj][0];
                        acc[jj][1] = h1 * wv + acc[jj][1];
                        acc[jj][2] = h2 * wv + acc[jj][2];
                        acc[jj][3] = h3 * wv + acc[jj][3];
                    }
                }
            }

            // horizontal add over k-parity; A indexed by o = (jj<<2)|r,
            // value is column j = jb + (jj ^ kch), row r.
            float A[16];
            #pragma unroll
            for (int o = 0; o < 16; ++o)
                A[o] = acc[o >> 2][o & 3].x + acc[o >> 2][o & 3].y;

            // 4-stage reduce-scatter over the 16 kc lanes, UNIFORM-FIRST
            // order (jj stages at 16/8 elems cost 2 ops/pair; keyed r
            // stages run last at 4/2 elems): 36 VALU vs 54 keyed-first.
            // stage kc-bit2 <-> jj-bit0 (uniform, swz xor4): keep jj0=0 slot
            float B[8];    // index (jj1<<2)|r
            #pragma unroll
            for (int i = 0; i < 8; ++i)
                B[i] = A[(i & 3) | ((i >> 2) << 3)]
                     + swz<0x101F>(A[(i & 3) | ((i >> 2) << 3) | 4]);
            // stage kc-bit3 <-> jj-bit1 (uniform, ror8 = xor8 in row16)
            float C[4];    // index r
            #pragma unroll
            for (int r = 0; r < 4; ++r)
                C[r] = B[r] + dpp_ror8(B[r + 4]);
            // stage kc-bit0 <-> r-bit0 (keyed keep/give)
            float D[2];
            #pragma unroll
            for (int i = 0; i < 2; ++i) {
                const float keep = pb0 ? C[2*i+1] : C[2*i];
                const float give = pb0 ? C[2*i]   : C[2*i+1];
                D[i] = keep + dpp_xor1(give);
            }
            // stage kc-bit1 <-> r-bit1 (keyed keep/give)
            const float keep = pb1 ? D[1] : D[0];
            const float give = pb1 ? D[0] : D[1];
            const float S = keep + dpp_xor2(give);

            wb[waddr] = fast_tanh(S + bh[ll]);
            __syncthreads();
        }

        // ---- output layer 128->6 for this wave's row; h3 lives in hp1.
        // Reduce-scatter s to lane s8 (uniform, XOR'd weights), all-reduce
        // the 8-lane groups, then readlane-broadcast p[0..5] as wave scalars.
        const float hA = hp1[oaddr + 2 * rw];
        const float hB = hp1[oaddr + 2 * rw + 288];
        float P[8];
        #pragma unroll
        for (int p = 0; p < 8; ++p) P[p] = hA * wo0p[p] + hB * wo1p[p];
        float Q[4];
        #pragma unroll
        for (int i = 0; i < 4; ++i) Q[i] = P[2*i] + dpp_xor1(P[2*i+1]);
        const float R0 = Q[0] + dpp_xor2(Q[1]);
        const float R1 = Q[2] + dpp_xor2(Q[3]);
        float S = R0 + swz<0x101F>(R1);   // xor4
        S += dpp_ror8(S);                 // xor8
        S += swz<0x401F>(S);              // xor16
        S += __shfl_xor(S, 32);           // xor32

        const float p0 = read_lane(S, 0);
        const float p1 = read_lane(S, 1);
        const float p2 = read_lane(S, 2);
        const float p3 = read_lane(S, 3);
        const float p4 = read_lane(S, 4);
        const float p5 = read_lane(S, 5);

        const float G = yc[0], I = yc[1], N = yc[2], L = yc[3], GE = yc[4], F = yc[5];
        d[0] = -0.01f*I*G + 0.05f*GE                                    + p0 + bo[0];
        d[1] = (G/(100.0f+G))*(1.0f + 2.0f*L/(5.0f+L)) - 0.1f*I         + p1 + bo[1];
        d[2] = -0.05f*N                                                 + p2 + bo[2];
        d[3] = 0.05f*GE - 0.2f*L                                        + p3 + bo[3];
        d[4] = m - 0.05f*GE                                             + p4 + bo[4];
        d[5] = -0.01f*I*F                                               + p5 + bo[5];
    };

    for (int i = 0; i < kT - 1; ++i) {
        const float t0 = t_span[i], t1 = t_span[i + 1];
        const float dt = t1 - t0;
        const float m0 = mrow[i], m1 = mrow[i + 1];
        const float v0 = vrow[i], v1 = vrow[i + 1];
        const float tm = t0 + 0.5f * dt;
        const float mm = 0.5f * (m0 + m1), vm = 0.5f * (v0 + v1);

        float d[6], ksum[6], yc[6];

        dyn(t0, y, m0, v0, d);
        #pragma unroll
        for (int s = 0; s < 6; ++s) { ksum[s] = d[s]; yc[s] = y[s] + 0.5f * dt * d[s]; }
        dyn(tm, yc, mm, vm, d);
        #pragma unroll
        for (int s = 0; s < 6; ++s) { ksum[s] += 2.0f * d[s]; yc[s] = y[s] + 0.5f * dt * d[s]; }
        dyn(tm, yc, mm, vm, d);
        #pragma unroll
        for (int s = 0; s < 6; ++s) { ksum[s] += 2.0f * d[s]; yc[s] = y[s] + dt * d[s]; }
        dyn(t1, yc, m1, v1, d);
        #pragma unroll
        for (int s = 0; s < 6; ++s) {
            ksum[s] += d[s];
            y[s] += (dt * (1.0f / 6.0f)) * ksum[s];
        }

        if (w < 4 && l == 0) {
            #pragma unroll
            for (int s = 0; s < 6; ++s)
                out[((size_t)row * kT + (i + 1)) * 6 + s] = y[s];
        }
    }
}

} // namespace

extern "C" void kernel_launch(void* const* d_in, const int* in_sizes, int n_in,
                              void* d_out, int out_size, void* d_ws, size_t ws_size,
                              hipStream_t stream) {
    const float* y0     = (const float*)d_in[0];
    const float* t_span = (const float*)d_in[1];
    const float* meal   = (const float*)d_in[2];
    const float* tvns   = (const float*)d_in[3];
    const float* W_in   = (const float*)d_in[4];
    const float* b_in   = (const float*)d_in[5];
    const float* W_h    = (const float*)d_in[6];
    const float* b_h    = (const float*)d_in[7];
    const float* W_out  = (const float*)d_in[8];
    const float* b_out  = (const float*)d_in[9];
    float* out          = (float*)d_out;

    hipLaunchKernelGGL(hybrid_ode_kernel, dim3(256), dim3(512), 0, stream,
                       y0, t_span, meal, tvns,
                       W_in, b_in, W_h, b_h, W_out, b_out, out);
}